// Round 8
// baseline (260.449 us; speedup 1.0000x reference)
//
#include <hip/hip_runtime.h>
#include <math.h>

#define H 4096
#define NE 64
#define KTOP 8
#define BT 64
#define TTOT 16384
#define NBLK (TTOT / BT)        // 256
#define TAU 1e-4f
#define DELTA 1e-3f

typedef __attribute__((ext_vector_type(8))) short bf16x8;
typedef __attribute__((ext_vector_type(4))) float f32x4;

union U4S8 { uint4 u; bf16x8 s; };

__device__ __forceinline__ unsigned bf16_rne(float f) {
  unsigned b = __float_as_uint(f);
  b += 0x7fffu + ((b >> 16) & 1u);
  return b >> 16;
}

// Convert w fp32 -> hi/lo bf16, pre-swizzled per-32k-chunk images (round-5
// proven). Image for chunk c: 256 uint4; uint4 index = e*4 + (s ^ ((e>>1)&3)),
// holding w[e][c*32 + s*8 .. +7]. hi = images 0..127, lo = +128*256.
__global__ __launch_bounds__(256) void w_prep(const float* __restrict__ w,
                                              uint4* __restrict__ wsimg) {
  const int sid = blockIdx.x * 256 + threadIdx.x;   // 0..32767
  const int e = sid >> 9;
  const int rem = sid & 511;
  const int c = rem >> 2;
  const int s = rem & 3;
  const float* src = w + (size_t)e * H + c * 32 + s * 8;
  float4 f0 = *(const float4*)src;
  float4 f1 = *(const float4*)(src + 4);
  float xf[8] = {f0.x, f0.y, f0.z, f0.w, f1.x, f1.y, f1.z, f1.w};
  unsigned hu[8], lu[8];
#pragma unroll
  for (int j = 0; j < 8; ++j) {
    hu[j] = bf16_rne(xf[j]);
    float hf = __uint_as_float(hu[j] << 16);
    lu[j] = bf16_rne(xf[j] - hf);
  }
  uint4 hp, lp;
  hp.x = hu[0] | (hu[1] << 16); hp.y = hu[2] | (hu[3] << 16);
  hp.z = hu[4] | (hu[5] << 16); hp.w = hu[6] | (hu[7] << 16);
  lp.x = lu[0] | (lu[1] << 16); lp.y = lu[2] | (lu[3] << 16);
  lp.z = lu[4] | (lu[5] << 16); lp.w = lu[6] | (lu[7] << 16);
  const int slotp = s ^ ((e >> 1) & 3);
  wsimg[(size_t)c * 256 + e * 4 + slotp] = hp;
  wsimg[(size_t)128 * 256 + (size_t)c * 256 + e * 4 + slotp] = lp;
}

// fp32x8 -> bf16 hi frag + residual lo frag (packed RNE cvt).
__device__ __forceinline__ void cvt_split(const float4 a, const float4 b,
                                          bf16x8* hi, bf16x8* lo) {
  float xf[8] = {a.x, a.y, a.z, a.w, b.x, b.y, b.z, b.w};
  unsigned ph[4], pl[4];
#pragma unroll
  for (int q = 0; q < 4; ++q)
    asm("v_cvt_pk_bf16_f32 %0, %1, %2" : "=v"(ph[q])
        : "v"(xf[2 * q]), "v"(xf[2 * q + 1]));
  float rs[8];
#pragma unroll
  for (int q = 0; q < 4; ++q) {
    rs[2 * q]     = xf[2 * q]     - __uint_as_float(ph[q] << 16);
    rs[2 * q + 1] = xf[2 * q + 1] - __uint_as_float(ph[q] & 0xffff0000u);
  }
#pragma unroll
  for (int q = 0; q < 4; ++q)
    asm("v_cvt_pk_bf16_f32 %0, %1, %2" : "=v"(pl[q])
        : "v"(rs[2 * q]), "v"(rs[2 * q + 1]));
  U4S8 h, l;
  h.u = (uint4){ph[0], ph[1], ph[2], ph[3]};
  l.u = (uint4){pl[0], pl[1], pl[2], pl[3]};
  *hi = h.s;
  *lo = l.s;
}

// LDS: double-buffered 64k K-step of w frags (hi+lo, both halves), unioned
// with the epilogue arrays (used only after all wbuf activity completes).
union __align__(16) SmemP1 {
  uint4 wbuf[2][2048];                                  // 65536 B
  struct { float lg[64 * 66]; float msum[8][64]; float cnt[8][64]; } ep;
};

// Pass 1: bf16-split MFMA router GEMM with counted-vmcnt pipeline.
// Per iter (64 k): consume x-ring slot u (chunk c) -> A-frags, THEN issue
// w(c+2) + x(c+4) prefetches, compute from LDS buf[c&1], ds_write w(c+1),
// then lgkmcnt(0)-only barrier (x/w prefetch loads stay in flight).
__global__ __launch_bounds__(512) void moe_pass1(
    const float* __restrict__ x, const uint4* __restrict__ wsimg,
    float* __restrict__ out, unsigned* __restrict__ wmask,
    float* __restrict__ waux) {
  __shared__ SmemP1 sm;
  const int tid = threadIdx.x;
  const int lane = tid & 63;
  const int wid = tid >> 6;
  const int tile = wid & 3;            // token tile 0..3 (16 tokens)
  const int kh = wid >> 2;             // K-half 0..1 (2048 each)
  const int tok0 = blockIdx.x * BT;
  const int trow = lane & 15;
  const int kgrp = lane >> 4;

  // staging role: thread covers 2 consecutive uint4 of each sub-image
  const int sh = tid >> 8;             // which K-half's images to stage
  const int shl = (tid >> 7) & 1;      // hi/lo
  const int sfl = tid & 127;
  const uint4* simgp = wsimg + (size_t)shl * (128 * 256);
  const int sbase = (sh * 2 + shl) * 256 + sfl * 2;   // LDS dest (even image)
  const int gbase = sh * 64;                           // 32k-image base

  const float* xp = x + (size_t)(tok0 + tile * 16 + trow) * H + kh * 2048 + kgrp * 8;

  // B-frag read offsets (round-5 swizzle)
  int eoff[4];
#pragma unroll
  for (int et = 0; et < 4; ++et) {
    const int e = et * 16 + trow;
    eoff[et] = e * 4 + (kgrp ^ ((e >> 1) & 3));
  }
  const int kb = kh * 512;

  f32x4 acc[4];
#pragma unroll
  for (int et = 0; et < 4; ++et) acc[et] = (f32x4){0.f, 0.f, 0.f, 0.f};

  // ---- prologue: wr[0]=K-step0, wr[1]=K-step1; x ring slots 0..3 ----
  uint4 wr[2][4];
#pragma unroll
  for (int p = 0; p < 2; ++p) {
    const int g0 = gbase + p * 2;
    wr[p][0] = simgp[(size_t)g0 * 256 + sfl * 2];
    wr[p][1] = simgp[(size_t)g0 * 256 + sfl * 2 + 1];
    wr[p][2] = simgp[(size_t)(g0 + 1) * 256 + sfl * 2];
    wr[p][3] = simgp[(size_t)(g0 + 1) * 256 + sfl * 2 + 1];
  }
  float4 xb0[4][2], xb1[4][2];
#pragma unroll
  for (int d = 0; d < 4; ++d)
#pragma unroll
    for (int s = 0; s < 2; ++s) {
      xb0[d][s] = *(const float4*)(xp + d * 64 + s * 32);
      xb1[d][s] = *(const float4*)(xp + d * 64 + s * 32 + 4);
    }
  // stage K-step 0 -> buf0 (full drain once; cheap)
  sm.wbuf[0][sbase]            = wr[0][0];
  sm.wbuf[0][sbase + 1]        = wr[0][1];
  sm.wbuf[0][1024 + sbase]     = wr[0][2];
  sm.wbuf[0][1024 + sbase + 1] = wr[0][3];
  __syncthreads();

  // ---- main loop: 32 iters of 64 k ----
#pragma unroll 1
  for (int cb = 0; cb < 32; cb += 4) {
#pragma unroll
    for (int u = 0; u < 4; ++u) {
      const int c = cb + u;
      // 0. consume x ring slot u (K-step c) into bf16 A-frags FIRST
      bf16x8 ah[2], al[2];
      cvt_split(xb0[u][0], xb1[u][0], &ah[0], &al[0]);
      cvt_split(xb0[u][1], xb1[u][1], &ah[1], &al[1]);
      // 1. w prefetch: K-step c+2 into wr[u&1] (consumed by iter c-1's write)
      if (c + 2 < 32) {
        const int g0 = gbase + (c + 2) * 2;
        wr[u & 1][0] = simgp[(size_t)g0 * 256 + sfl * 2];
        wr[u & 1][1] = simgp[(size_t)g0 * 256 + sfl * 2 + 1];
        wr[u & 1][2] = simgp[(size_t)(g0 + 1) * 256 + sfl * 2];
        wr[u & 1][3] = simgp[(size_t)(g0 + 1) * 256 + sfl * 2 + 1];
      }
      // 2. x prefetch: K-step c+4 into ring slot u (now free)
      if (c + 4 < 32) {
#pragma unroll
        for (int s = 0; s < 2; ++s) {
          xb0[u][s] = *(const float4*)(xp + (c + 4) * 64 + s * 32);
          xb1[u][s] = *(const float4*)(xp + (c + 4) * 64 + s * 32 + 4);
        }
      }
      // 3. compute K-step c from buf[u&1]
#pragma unroll
      for (int s = 0; s < 2; ++s) {
        U4S8 bh[4], bl[4];
#pragma unroll
        for (int et = 0; et < 4; ++et) {
          bh[et].u = sm.wbuf[u & 1][s * 1024 + kb + eoff[et]];
          bl[et].u = sm.wbuf[u & 1][s * 1024 + kb + 256 + eoff[et]];
        }
#pragma unroll
        for (int et = 0; et < 4; ++et) {
          acc[et] = __builtin_amdgcn_mfma_f32_16x16x32_bf16(ah[s], bh[et].s, acc[et], 0, 0, 0);
          acc[et] = __builtin_amdgcn_mfma_f32_16x16x32_bf16(ah[s], bl[et].s, acc[et], 0, 0, 0);
          acc[et] = __builtin_amdgcn_mfma_f32_16x16x32_bf16(al[s], bh[et].s, acc[et], 0, 0, 0);
        }
      }
      // 4. stage K-step c+1 (loaded at iter c-1) into the other buffer
      if (c + 1 < 32) {
        const int wd = (u + 1) & 1;
        sm.wbuf[wd][sbase]            = wr[wd][0];
        sm.wbuf[wd][sbase + 1]        = wr[wd][1];
        sm.wbuf[wd][1024 + sbase]     = wr[wd][2];
        sm.wbuf[wd][1024 + sbase + 1] = wr[wd][3];
      }
      // 5. barrier WITHOUT vmcnt drain: ds ops retired, prefetches in flight
      asm volatile("s_waitcnt lgkmcnt(0)" ::: "memory");
      __builtin_amdgcn_s_barrier();
      asm volatile("" ::: "memory");
    }
  }

  // ---- cross-half reduce (aliases wbuf; all wbuf activity drained above) ----
  if (kh == 1) {
#pragma unroll
    for (int et = 0; et < 4; ++et)
#pragma unroll
      for (int r = 0; r < 4; ++r)
        sm.ep.lg[(tile * 16 + kgrp * 4 + r) * 66 + et * 16 + trow] = acc[et][r];
  }
  __syncthreads();
  if (kh == 0) {
#pragma unroll
    for (int et = 0; et < 4; ++et)
#pragma unroll
      for (int r = 0; r < 4; ++r) {
        const int li = (tile * 16 + kgrp * 4 + r) * 66 + et * 16 + trow;
        sm.ep.lg[li] += acc[et][r];
      }
  }
  __syncthreads();

  // ---- epilogue: 8 waves x 8 tokens, lane = expert (round-5 proven) ----
  float msum = 0.f;
  int cnt = 0;
#pragma unroll 1
  for (int it = 0; it < 8; ++it) {
    const int t = wid * 8 + it;
    const float lf = sm.ep.lg[t * 66 + lane];

    float m = lf;
#pragma unroll
    for (int off = 32; off; off >>= 1) m = fmaxf(m, __shfl_xor(m, off));
    float p = expf(lf - m);
    float s = p;
#pragma unroll
    for (int off = 32; off; off >>= 1) s += __shfl_xor(s, off);
    msum += p / s;

    // top-9 by logit, descending, tie -> lowest index
    float cur = lf;
    float myv = 0.f;
    int myi = 0;
#pragma unroll
    for (int r = 0; r < 9; ++r) {
      float v = cur;
      int ix = lane;
#pragma unroll
      for (int off = 1; off < 64; off <<= 1) {
        float ov = __shfl_xor(v, off);
        int oi = __shfl_xor(ix, off);
        if (ov > v || (ov == v && oi < ix)) { v = ov; ix = oi; }
      }
      if (lane == r) { myv = v; myi = ix; }
      if (r < 8 && lane == ix) { cur = -INFINITY; ++cnt; }
    }

    const float m0 = __shfl(myv, 0);
    float e = expf(myv - m0);
    float sv = e;
    sv += __shfl_xor(sv, 1);
    sv += __shfl_xor(sv, 2);
    sv += __shfl_xor(sv, 4);
    const float wgtv = e / sv;
    const int tg = tok0 + t;
    if (lane < KTOP) {
      out[(size_t)tg * KTOP + lane] = (float)myi;
      out[(size_t)TTOT * KTOP + (size_t)tg * KTOP + lane] = wgtv;
    }

    const float nxt = __shfl(myv, (lane + 1) & 63);
    const bool gp = (lane < 8) && (myv - nxt < TAU);
    const unsigned long long anyg = __ballot(gp);
    const float v7 = __shfl(myv, 7);
    const unsigned long long msk = __ballot(lf >= v7 - DELTA);
    if (lane == 0) {
      const unsigned long long mv = anyg ? msk : 0ULL;
      wmask[tg] = (unsigned)mv;
      wmask[TTOT + tg] = (unsigned)(mv >> 32);
    }
  }
  sm.ep.msum[wid][lane] = msum;
  sm.ep.cnt[wid][lane] = (float)cnt;
  __syncthreads();
  if (tid < 64) {
    float c8 = 0.f, m8 = 0.f;
#pragma unroll
    for (int k = 0; k < 8; ++k) { c8 += sm.ep.cnt[k][tid]; m8 += sm.ep.msum[k][tid]; }
    waux[blockIdx.x * 128 + tid] = c8;
    waux[blockIdx.x * 128 + 64 + tid] = m8;
  }
}

// Pass 2: fp64 recompute of candidate experts for flagged tokens only.
__global__ __launch_bounds__(256) void moe_pass2(
    const float* __restrict__ x, const float* __restrict__ w,
    const unsigned* __restrict__ wmask, float* __restrict__ out) {
  __shared__ unsigned slo[64], shi[64];
  __shared__ double red[4];
  __shared__ double cval[64];
  __shared__ int cidx[64];
  const int tid = threadIdx.x;
  const int lane = tid & 63, wid = tid >> 6;
  const int t0 = blockIdx.x * BT;

  if (tid < 64) { slo[tid] = wmask[t0 + tid]; shi[tid] = wmask[TTOT + t0 + tid]; }
  __syncthreads();
  int myf = (tid < 64) ? ((slo[tid] | shi[tid]) != 0u) : 0;
  if (!__syncthreads_or(myf)) return;

#pragma unroll 1
  for (int tt = 0; tt < BT; ++tt) {
    const unsigned lo = slo[tt], hi = shi[tt];
    if (!(lo | hi)) continue;
    const int t = t0 + tt;
    const unsigned long long m = ((unsigned long long)hi << 32) | lo;
    const float* xr = x + (size_t)t * H;
    int ncand = 0;
#pragma unroll 1
    for (int e = 0; e < 64; ++e) {
      if (!((m >> e) & 1ULL)) continue;
      const float* wr = w + (size_t)e * H;
      double d = 0.0;
#pragma unroll
      for (int q = 0; q < 16; ++q) {
        const int k = tid + 256 * q;
        d = fma((double)xr[k], (double)wr[k], d);
      }
#pragma unroll
      for (int off = 32; off; off >>= 1) d += __shfl_xor(d, off);
      if (lane == 0) red[wid] = d;
      __syncthreads();
      if (tid == 0) {
        cval[ncand] = red[0] + red[1] + red[2] + red[3];
        cidx[ncand] = e;
      }
      __syncthreads();
      ++ncand;
    }
    if (tid == 0) {
      double sel[8];
      int si[8];
      for (int r = 0; r < 8; ++r) {
        int best = 0;
        double bv = -1e300;
        for (int c2 = 0; c2 < ncand; ++c2)
          if (cval[c2] > bv) { bv = cval[c2]; best = c2; }
        sel[r] = cval[best]; si[r] = cidx[best];
        cval[best] = -1e301;
      }
      const double m0 = sel[0];
      float es[8], ssum = 0.f;
      for (int r = 0; r < 8; ++r) { es[r] = expf((float)(sel[r] - m0)); ssum += es[r]; }
      for (int r = 0; r < 8; ++r) {
        out[(size_t)t * KTOP + r] = (float)si[r];
        out[(size_t)TTOT * KTOP + (size_t)t * KTOP + r] = es[r] / ssum;
      }
    }
    __syncthreads();
  }
}

// aux = alpha * mean_b sum_e (count[b,e]/(S*K/E)) * (scoresum[b,e]/S)
__global__ __launch_bounds__(256) void moe_gate_aux(
    const float* __restrict__ waux, float* __restrict__ out) {
  const int tid = threadIdx.x;
  const int b = tid >> 6, e = tid & 63;
  float cnt = 0.f, ms = 0.f;
#pragma unroll 4
  for (int j = 0; j < 64; ++j) {
    const int blk = b * 64 + j;
    cnt += waux[blk * 128 + e];
    ms += waux[blk * 128 + 64 + e];
  }
  float term = (cnt * (1.f / 512.f)) * (ms * (1.f / 4096.f));
  __shared__ float red[4];
#pragma unroll
  for (int off = 32; off; off >>= 1) term += __shfl_xor(term, off);
  if ((tid & 63) == 0) red[tid >> 6] = term;
  __syncthreads();
  if (tid == 0) {
    float tot = red[0] + red[1] + red[2] + red[3];
    out[(size_t)TTOT * KTOP * 2] = tot * (0.001f / 4.f);
  }
}

extern "C" void kernel_launch(void* const* d_in, const int* in_sizes, int n_in,
                              void* d_out, int out_size, void* d_ws, size_t ws_size,
                              hipStream_t stream) {
  (void)in_sizes; (void)n_in; (void)out_size; (void)ws_size;
  const float* x = (const float*)d_in[0];
  const float* w = (const float*)d_in[1];
  float* out = (float*)d_out;
  uint4* wsimg = (uint4*)d_ws;                                   // 1 MB hi+lo images
  unsigned* wmask = (unsigned*)((char*)d_ws + (1 << 20));        // 128 KB
  float* waux = (float*)((char*)d_ws + (1 << 20) + 2 * TTOT * 4);// 128 KB
  w_prep<<<128, 256, 0, stream>>>(w, wsimg);
  moe_pass1<<<NBLK, 512, 0, stream>>>(x, wsimg, out, wmask, waux);
  moe_pass2<<<NBLK, 256, 0, stream>>>(x, w, wmask, out);
  moe_gate_aux<<<1, 256, 0, stream>>>(waux, out);
}

// Round 9
// 240.186 us; speedup vs baseline: 1.0844x; 1.0844x over previous
//
#include <hip/hip_runtime.h>
#include <math.h>

#define H 4096
#define NE 64
#define KTOP 8
#define BT 64
#define TTOT 16384
#define NBLK (TTOT / BT)        // 256
#define TAU 1e-4f
#define DELTA 1e-3f

typedef __attribute__((ext_vector_type(8))) short bf16x8;
typedef __attribute__((ext_vector_type(4))) float f32x4;

union U4S8 { uint4 u; bf16x8 s; };

__device__ __forceinline__ unsigned bf16_rne(float f) {
  unsigned b = __float_as_uint(f);
  b += 0x7fffu + ((b >> 16) & 1u);
  return b >> 16;
}

// w fp32 -> hi/lo bf16, pre-swizzled per-32k-chunk images (round-5 proven).
// Chunk c image: 256 uint4; index = e*4 + (s ^ ((e>>1)&3)), holding
// w[e][c*32 + s*8 .. +7]. hi = images 0..127, lo = +128*256 uint4.
__global__ __launch_bounds__(256) void w_prep(const float* __restrict__ w,
                                              uint4* __restrict__ wsimg) {
  const int sid = blockIdx.x * 256 + threadIdx.x;   // 0..32767
  const int e = sid >> 9;
  const int rem = sid & 511;
  const int c = rem >> 2;
  const int s = rem & 3;
  const float* src = w + (size_t)e * H + c * 32 + s * 8;
  float4 f0 = *(const float4*)src;
  float4 f1 = *(const float4*)(src + 4);
  float xf[8] = {f0.x, f0.y, f0.z, f0.w, f1.x, f1.y, f1.z, f1.w};
  unsigned hu[8], lu[8];
#pragma unroll
  for (int j = 0; j < 8; ++j) {
    hu[j] = bf16_rne(xf[j]);
    float hf = __uint_as_float(hu[j] << 16);
    lu[j] = bf16_rne(xf[j] - hf);
  }
  uint4 hp, lp;
  hp.x = hu[0] | (hu[1] << 16); hp.y = hu[2] | (hu[3] << 16);
  hp.z = hu[4] | (hu[5] << 16); hp.w = hu[6] | (hu[7] << 16);
  lp.x = lu[0] | (lu[1] << 16); lp.y = lu[2] | (lu[3] << 16);
  lp.z = lu[4] | (lu[5] << 16); lp.w = lu[6] | (lu[7] << 16);
  const int slotp = s ^ ((e >> 1) & 3);
  wsimg[(size_t)c * 256 + e * 4 + slotp] = hp;
  wsimg[(size_t)128 * 256 + (size_t)c * 256 + e * 4 + slotp] = lp;
}

// fp32x8 -> bf16 hi frag + residual lo frag (packed RNE cvt).
__device__ __forceinline__ void cvt_split(const float4 a, const float4 b,
                                          bf16x8* hi, bf16x8* lo) {
  float xf[8] = {a.x, a.y, a.z, a.w, b.x, b.y, b.z, b.w};
  unsigned ph[4], pl[4];
#pragma unroll
  for (int q = 0; q < 4; ++q)
    asm("v_cvt_pk_bf16_f32 %0, %1, %2" : "=v"(ph[q])
        : "v"(xf[2 * q]), "v"(xf[2 * q + 1]));
  float rs[8];
#pragma unroll
  for (int q = 0; q < 4; ++q) {
    rs[2 * q]     = xf[2 * q]     - __uint_as_float(ph[q] << 16);
    rs[2 * q + 1] = xf[2 * q + 1] - __uint_as_float(ph[q] & 0xffff0000u);
  }
#pragma unroll
  for (int q = 0; q < 4; ++q)
    asm("v_cvt_pk_bf16_f32 %0, %1, %2" : "=v"(pl[q])
        : "v"(rs[2 * q]), "v"(rs[2 * q + 1]));
  U4S8 h, l;
  h.u = (uint4){ph[0], ph[1], ph[2], ph[3]};
  l.u = (uint4){pl[0], pl[1], pl[2], pl[3]};
  *hi = h.s;
  *lo = l.s;
}

#define GLDS(GP, LP)                                                   \
  __builtin_amdgcn_global_load_lds(                                    \
      (const __attribute__((address_space(1))) void*)(GP),             \
      (__attribute__((address_space(3))) void*)(LP), 16, 0, 0)

// Pass 1: bf16-split MFMA router GEMM, 4-deep global_load_lds pipeline.
// LDS buffer per K-step (32 KB): [0,16K) x fp32 tile 64x64 (row-XOR-swizzled
// via pre-swizzled global src), [16K,32K) w frag images (hi/lo x 2 chunks).
// Per iter: vmcnt(16) (keep 2 steps in flight), s_barrier, issue step c+3,
// compute step c. 4 waves; wave = 16 tokens x 64 experts x full K.
__global__ __launch_bounds__(256, 1) void moe_pass1(
    const float* __restrict__ x, const uint4* __restrict__ wsimg,
    float* __restrict__ out, unsigned* __restrict__ wmask,
    float* __restrict__ waux) {
  extern __shared__ __align__(16) char smraw[];
  const int tid = threadIdx.x;
  const int lane = tid & 63;
  const int wid = tid >> 6;          // wave 0..3 = token tile
  const int tok0 = blockIdx.x * BT;
  const int trow = lane & 15;
  const int kgrp = lane >> 4;

  // ---- staging source pointers (per thread) ----
  // x: issue j covers lds bytes [j*4096 + tid*16, +16) of the x tile.
  const char* xsrc[4];
#pragma unroll
  for (int j = 0; j < 4; ++j) {
    const int Lb = j * 4096 + tid * 16;
    const int row = Lb >> 8;                    // 0..63
    const int inrow = Lb & 255;
    const int sin = inrow ^ ((row & 7) << 4);   // pre-swizzled source
    xsrc[j] = (const char*)(x + (size_t)(tok0 + row) * H) + sin;
  }
  // w: issue j -> region j: hilo=j>>1, chunk-in-step=j&1; linear copy.
  const uint4* wsrc[4];
#pragma unroll
  for (int j = 0; j < 4; ++j)
    wsrc[j] = wsimg + (size_t)(j >> 1) * (128 * 256) + (j & 1) * 256 + tid;

  f32x4 acc[4];
#pragma unroll
  for (int et = 0; et < 4; ++et) acc[et] = (f32x4){0.f, 0.f, 0.f, 0.f};

#define ISSUE_STEP(KC, BUF)                                             \
  do {                                                                  \
    char* bb = smraw + (BUF) * 32768 + (wid << 10);                     \
    _Pragma("unroll") for (int j = 0; j < 4; ++j)                       \
      GLDS(xsrc[j] + (size_t)(KC) * 256, bb + j * 4096);                \
    _Pragma("unroll") for (int j = 0; j < 4; ++j)                       \
      GLDS((const char*)(wsrc[j] + (size_t)(KC) * 512),                 \
           bb + 16384 + j * 4096);                                      \
  } while (0)

  // ---- prologue: fill buffers 0,1,2 (24 loads in flight) ----
  ISSUE_STEP(0, 0);
  ISSUE_STEP(1, 1);
  ISSUE_STEP(2, 2);

  // read-side constants
  const int arow = wid * 16 + trow;
  const int sx = (trow & 7) << 4;              // arow&7 == trow&7
  const int abase = arow * 256 + kgrp * 32;
  int entry[4];
#pragma unroll
  for (int et = 0; et < 4; ++et) {
    const int e = et * 16 + trow;
    entry[et] = (e * 4 + (kgrp ^ ((e >> 1) & 3))) * 16;
  }

  // ---- main loop: 64 K-steps of 64 k ----
#pragma unroll 1
  for (int kc = 0; kc < 64; ++kc) {
    if (kc < 62) {
      asm volatile("s_waitcnt vmcnt(16)" ::: "memory");
    } else if (kc == 62) {
      asm volatile("s_waitcnt vmcnt(8)" ::: "memory");
    } else {
      asm volatile("s_waitcnt vmcnt(0)" ::: "memory");
    }
    __builtin_amdgcn_s_barrier();
    asm volatile("" ::: "memory");
    if (kc + 3 < 64) ISSUE_STEP(kc + 3, (kc + 3) & 3);

    const char* bufp = smraw + (kc & 3) * 32768;
#pragma unroll
    for (int sub = 0; sub < 2; ++sub) {
      float4 v0 = *(const float4*)(bufp + ((abase + sub * 128) ^ sx));
      float4 v1 = *(const float4*)(bufp + ((abase + sub * 128 + 16) ^ sx));
      bf16x8 ah, al;
      cvt_split(v0, v1, &ah, &al);
#pragma unroll
      for (int et = 0; et < 4; ++et) {
        U4S8 bh, bl;
        bh.u = *(const uint4*)(bufp + 16384 + sub * 4096 + entry[et]);
        bl.u = *(const uint4*)(bufp + 16384 + (2 + sub) * 4096 + entry[et]);
        acc[et] = __builtin_amdgcn_mfma_f32_16x16x32_bf16(ah, bh.s, acc[et], 0, 0, 0);
        acc[et] = __builtin_amdgcn_mfma_f32_16x16x32_bf16(ah, bl.s, acc[et], 0, 0, 0);
        acc[et] = __builtin_amdgcn_mfma_f32_16x16x32_bf16(al, bh.s, acc[et], 0, 0, 0);
      }
    }
  }

  // ---- logits to LDS (aliases buffers; vmcnt fully drained at kc=63) ----
  __syncthreads();
  float* lg = (float*)smraw;                    // [64][66]
  float* msumA = (float*)(smraw + 16896);       // [4][64]
  float* cntA = (float*)(smraw + 17920);        // [4][64]
#pragma unroll
  for (int et = 0; et < 4; ++et)
#pragma unroll
    for (int r = 0; r < 4; ++r)
      lg[(wid * 16 + kgrp * 4 + r) * 66 + et * 16 + trow] = acc[et][r];
  __syncthreads();

  // ---- epilogue: 4 waves x 16 tokens, lane = expert (round-5 proven) ----
  float msum = 0.f;
  int cnt = 0;
#pragma unroll 1
  for (int it = 0; it < 16; ++it) {
    const int t = wid * 16 + it;
    const float lf = lg[t * 66 + lane];

    float m = lf;
#pragma unroll
    for (int off = 32; off; off >>= 1) m = fmaxf(m, __shfl_xor(m, off));
    float p = expf(lf - m);
    float s = p;
#pragma unroll
    for (int off = 32; off; off >>= 1) s += __shfl_xor(s, off);
    msum += p / s;

    // top-9 by logit, descending, tie -> lowest index
    float cur = lf;
    float myv = 0.f;
    int myi = 0;
#pragma unroll
    for (int r = 0; r < 9; ++r) {
      float v = cur;
      int ix = lane;
#pragma unroll
      for (int off = 1; off < 64; off <<= 1) {
        float ov = __shfl_xor(v, off);
        int oi = __shfl_xor(ix, off);
        if (ov > v || (ov == v && oi < ix)) { v = ov; ix = oi; }
      }
      if (lane == r) { myv = v; myi = ix; }
      if (r < 8 && lane == ix) { cur = -INFINITY; ++cnt; }
    }

    const float m0 = __shfl(myv, 0);
    float e = expf(myv - m0);
    float sv = e;
    sv += __shfl_xor(sv, 1);
    sv += __shfl_xor(sv, 2);
    sv += __shfl_xor(sv, 4);
    const float wgtv = e / sv;
    const int tg = tok0 + t;
    if (lane < KTOP) {
      out[(size_t)tg * KTOP + lane] = (float)myi;
      out[(size_t)TTOT * KTOP + (size_t)tg * KTOP + lane] = wgtv;
    }

    const float nxt = __shfl(myv, (lane + 1) & 63);
    const bool gp = (lane < 8) && (myv - nxt < TAU);
    const unsigned long long anyg = __ballot(gp);
    const float v7 = __shfl(myv, 7);
    const unsigned long long msk = __ballot(lf >= v7 - DELTA);
    if (lane == 0) {
      const unsigned long long mv = anyg ? msk : 0ULL;
      wmask[tg] = (unsigned)mv;
      wmask[TTOT + tg] = (unsigned)(mv >> 32);
    }
  }
  msumA[wid * 64 + lane] = msum;
  cntA[wid * 64 + lane] = (float)cnt;
  __syncthreads();
  if (tid < 64) {
    float c4 = 0.f, m4 = 0.f;
#pragma unroll
    for (int k = 0; k < 4; ++k) {
      c4 += cntA[k * 64 + tid];
      m4 += msumA[k * 64 + tid];
    }
    waux[blockIdx.x * 128 + tid] = c4;
    waux[blockIdx.x * 128 + 64 + tid] = m4;
  }
}

// Pass 2: fp64 recompute of candidate experts for flagged tokens only.
__global__ __launch_bounds__(256) void moe_pass2(
    const float* __restrict__ x, const float* __restrict__ w,
    const unsigned* __restrict__ wmask, float* __restrict__ out) {
  __shared__ unsigned slo[64], shi[64];
  __shared__ double red[4];
  __shared__ double cval[64];
  __shared__ int cidx[64];
  const int tid = threadIdx.x;
  const int lane = tid & 63, wid = tid >> 6;
  const int t0 = blockIdx.x * BT;

  if (tid < 64) { slo[tid] = wmask[t0 + tid]; shi[tid] = wmask[TTOT + t0 + tid]; }
  __syncthreads();
  int myf = (tid < 64) ? ((slo[tid] | shi[tid]) != 0u) : 0;
  if (!__syncthreads_or(myf)) return;

#pragma unroll 1
  for (int tt = 0; tt < BT; ++tt) {
    const unsigned lo = slo[tt], hi = shi[tt];
    if (!(lo | hi)) continue;
    const int t = t0 + tt;
    const unsigned long long m = ((unsigned long long)hi << 32) | lo;
    const float* xr = x + (size_t)t * H;
    int ncand = 0;
#pragma unroll 1
    for (int e = 0; e < 64; ++e) {
      if (!((m >> e) & 1ULL)) continue;
      const float* wr = w + (size_t)e * H;
      double d = 0.0;
#pragma unroll
      for (int q = 0; q < 16; ++q) {
        const int k = tid + 256 * q;
        d = fma((double)xr[k], (double)wr[k], d);
      }
#pragma unroll
      for (int off = 32; off; off >>= 1) d += __shfl_xor(d, off);
      if (lane == 0) red[wid] = d;
      __syncthreads();
      if (tid == 0) {
        cval[ncand] = red[0] + red[1] + red[2] + red[3];
        cidx[ncand] = e;
      }
      __syncthreads();
      ++ncand;
    }
    if (tid == 0) {
      double sel[8];
      int si[8];
      for (int r = 0; r < 8; ++r) {
        int best = 0;
        double bv = -1e300;
        for (int c2 = 0; c2 < ncand; ++c2)
          if (cval[c2] > bv) { bv = cval[c2]; best = c2; }
        sel[r] = cval[best]; si[r] = cidx[best];
        cval[best] = -1e301;
      }
      const double m0 = sel[0];
      float es[8], ssum = 0.f;
      for (int r = 0; r < 8; ++r) { es[r] = expf((float)(sel[r] - m0)); ssum += es[r]; }
      for (int r = 0; r < 8; ++r) {
        out[(size_t)t * KTOP + r] = (float)si[r];
        out[(size_t)TTOT * KTOP + (size_t)t * KTOP + r] = es[r] / ssum;
      }
    }
    __syncthreads();
  }
}

// aux = alpha * mean_b sum_e (count[b,e]/(S*K/E)) * (scoresum[b,e]/S)
__global__ __launch_bounds__(256) void moe_gate_aux(
    const float* __restrict__ waux, float* __restrict__ out) {
  const int tid = threadIdx.x;
  const int b = tid >> 6, e = tid & 63;
  float cnt = 0.f, ms = 0.f;
#pragma unroll 4
  for (int j = 0; j < 64; ++j) {
    const int blk = b * 64 + j;
    cnt += waux[blk * 128 + e];
    ms += waux[blk * 128 + 64 + e];
  }
  float term = (cnt * (1.f / 512.f)) * (ms * (1.f / 4096.f));
  __shared__ float red[4];
#pragma unroll
  for (int off = 32; off; off >>= 1) term += __shfl_xor(term, off);
  if ((tid & 63) == 0) red[tid >> 6] = term;
  __syncthreads();
  if (tid == 0) {
    float tot = red[0] + red[1] + red[2] + red[3];
    out[(size_t)TTOT * KTOP * 2] = tot * (0.001f / 4.f);
  }
}

extern "C" void kernel_launch(void* const* d_in, const int* in_sizes, int n_in,
                              void* d_out, int out_size, void* d_ws, size_t ws_size,
                              hipStream_t stream) {
  (void)in_sizes; (void)n_in; (void)out_size; (void)ws_size;
  const float* x = (const float*)d_in[0];
  const float* w = (const float*)d_in[1];
  float* out = (float*)d_out;
  uint4* wsimg = (uint4*)d_ws;                                   // 1 MB hi + 1 MB lo
  unsigned* wmask = (unsigned*)((char*)d_ws + (1 << 21));        // 128 KB
  float* waux = (float*)((char*)d_ws + (1 << 21) + 2 * TTOT * 4);// 128 KB
  (void)hipFuncSetAttribute((const void*)moe_pass1,
                            hipFuncAttributeMaxDynamicSharedMemorySize, 131072);
  w_prep<<<128, 256, 0, stream>>>(w, wsimg);
  moe_pass1<<<NBLK, 256, 131072, stream>>>(x, wsimg, out, wmask, waux);
  moe_pass2<<<NBLK, 256, 0, stream>>>(x, w, wmask, out);
  moe_gate_aux<<<1, 256, 0, stream>>>(waux, out);
}